// Round 16
// baseline (76.593 us; speedup 1.0000x reference)
//
#include <hip/hip_runtime.h>
#include <hip/hip_bf16.h>

#define NDIM 256
#define NN (NDIM*NDIM)

typedef __attribute__((ext_vector_type(8))) short s8bf;    // 8 x bf16 (4 VGPRs)
typedef __attribute__((ext_vector_type(4))) float f32x4;   // MFMA accum / native float4

__device__ __forceinline__ unsigned short f2bf(float f) {
    union { float f; unsigned u; } v; v.f = f;
    unsigned u = v.u;
    return (unsigned short)((u + 0x7FFFu + ((u >> 16) & 1u)) >> 16);  // RNE
}
__device__ __forceinline__ short f2bfs(float f) {          // compiler emits v_cvt_pk_bf16_f32
    __hip_bfloat16 h = __float2bfloat16(f);
    union { __hip_bfloat16 h; short s; } v; v.h = h;
    return v.s;
}

// ---------------- expm pipeline: U = B0 + M3*(B1 + M3/720) ----------------
// M = H1 - i*H0. deg-6 Taylor; truncation ~1e-4 << bf16 noise.
// 1024 thr (16,16,4): K split 4 ways across tz + 2-way sub-accumulators.
__global__ __launch_bounds__(1024) void kmm(
    const float* __restrict__ H, float2* __restrict__ M2c, float2* __restrict__ M3c,
    unsigned short* __restrict__ Ut, int mode) {
    __shared__ float2 As[16][257];
    __shared__ float2 Bs[256][17];
    __shared__ float2 Rs[3][16][17];
    const int tx = threadIdx.x, ty = threadIdx.y, tz = threadIdx.z;
    const int tid = (tz * 16 + ty) * 16 + tx;
    const int r0 = blockIdx.y * 16, c0 = blockIdx.x * 16;

#pragma unroll
    for (int i = 0; i < 4; ++i) {               // A panel: 16 rows x 256 k
        int idx = i * 1024 + tid;
        int r = idx >> 8, k = idx & 255;
        float2 a;
        if (mode == 0)      { a.x = H[NN + (r0+r)*NDIM + k]; a.y = -H[(r0+r)*NDIM + k]; }
        else if (mode == 1) a = M2c[(r0+r)*NDIM + k];
        else                a = M3c[(r0+r)*NDIM + k];
        As[r][k] = a;
    }
#pragma unroll
    for (int i = 0; i < 4; ++i) {               // B panel: 256 k x 16 cols
        int idx = i * 1024 + tid;
        int k = idx >> 4, cc = idx & 15;
        float2 b;
        if (mode <= 1) { b.x = H[NN + k*NDIM + c0+cc]; b.y = -H[k*NDIM + c0+cc]; }
        else {
            int g = k * NDIM + c0 + cc;
            float mr = H[NN + g], mi = -H[g];
            float2 m2 = M2c[g], m3 = M3c[g];
            float di = (k == c0 + cc) ? 1.f : 0.f;
            b.x = di*(1.f/6.f) + mr*(1.f/24.f) + m2.x*(1.f/120.f) + m3.x*(1.f/720.f);
            b.y =                mi*(1.f/24.f) + m2.y*(1.f/120.f) + m3.y*(1.f/720.f);
        }
        Bs[k][cc] = b;
    }
    __syncthreads();

    float sr0=0.f, si0=0.f, sr1=0.f, si1=0.f;
#pragma unroll 8
    for (int k = tz*64; k < tz*64 + 64; k += 2) {
        float2 a = As[ty][k], b = Bs[k][tx];
        sr0 = fmaf(a.x, b.x, sr0); sr0 = fmaf(-a.y, b.y, sr0);
        si0 = fmaf(a.x, b.y, si0); si0 = fmaf(a.y, b.x, si0);
        float2 a1 = As[ty][k+1], b1 = Bs[k+1][tx];
        sr1 = fmaf(a1.x, b1.x, sr1); sr1 = fmaf(-a1.y, b1.y, sr1);
        si1 = fmaf(a1.x, b1.y, si1); si1 = fmaf(a1.y, b1.x, si1);
    }
    float sr = sr0 + sr1, si = si0 + si1;
    if (tz > 0) Rs[tz-1][ty][tx] = make_float2(sr, si);
    __syncthreads();
    if (tz == 0) {
        sr += Rs[0][ty][tx].x + Rs[1][ty][tx].x + Rs[2][ty][tx].x;
        si += Rs[0][ty][tx].y + Rs[1][ty][tx].y + Rs[2][ty][tx].y;
        int d = r0 + ty, e = c0 + tx;
        if (mode == 0)      M2c[d*NDIM + e] = make_float2(sr, si);
        else if (mode == 1) M3c[d*NDIM + e] = make_float2(sr, si);
        else {
            int g = d * NDIM + e;
            float ur = sr + ((d == e) ? 1.f : 0.f) + H[NN + g] + M2c[g].x * 0.5f;
            Ut[e * NDIM + d] = f2bf(ur);         // transposed: Ut[col][k]
        }
    }
}

// ---- kgemm helpers (inlined; callers fully unrolled -> all indices const) ----
__device__ __forceinline__ void main_step(
    int s, const f32x4* psi4, const s8bf* Bg, int c, int q,
    size_t rl, size_t rlN, f32x4 pb[2][2], f32x4 acc[16]) {
    s8bf a;
#pragma unroll
    for (int j = 0; j < 4; ++j) {
        a[j]     = f2bfs(pb[s & 1][0][j]);
        a[j + 4] = f2bfs(pb[s & 1][1][j]);
    }
    if (s < 6) {                                 // refill slot for step s+2
        int o = (s + 2) * 8 + q * 2;
        pb[s & 1][0] = psi4[rl + o];
        pb[s & 1][1] = psi4[rl + o + 1];
    } else {                                     // s=6,7: prime NEXT strip's ring
        int o = (s - 6) * 8 + q * 2;
        pb[s & 1][0] = psi4[rlN + o];
        pb[s & 1][1] = psi4[rlN + o + 1];
    }
#pragma unroll
    for (int ct = 0; ct < 16; ++ct) {
        int rr = ct * 16 + c;
        s8bf bb = Bg[(rr << 5) | ((s * 4 + q) ^ (rr & 7))];
        acc[ct] = __builtin_amdgcn_mfma_f32_16x16x32_bf16(a, bb, acc[ct], 0, 0, 0);
    }
}

__device__ __forceinline__ void epi_pass(
    int p, int c, int q, int lane, float* Ebase, const f32x4 acc[16],
    f32x4* out4, int baseP) {
    const int qq = p >> 2, rr = p & 3;
    float* E = Ebase + (p & 1) * 256;            // ping-pong halves (distance-2)
    if (q == qq) {
#pragma unroll
        for (int ct = 0; ct < 16; ++ct) E[ct * 16 + c] = acc[ct][rr];
    }
    f32x4 vv = *(const f32x4*)(&E[lane * 4]);
    __builtin_nontemporal_store(vv, &out4[(size_t)(baseP + p) * 64 + lane]);
    __builtin_amdgcn_sched_barrier(0);   // PIN: WAR safety for distance-2 reuse
}                                        // (R4/R15 raced without this; R5/R6 proven with it)

// ---------------- main GEMM: out[131072 x 256] = psi @ Re(U) ----------------
// Strip-pipelined R6 (pins RESTORED): 512 thr = 8 waves x 16 rows x 4 strips
// of 128 rows. Strips alternate accA/accB; strip k's 8 MFMA-steps interleave
// strip k-1's 16 epilogue passes (2/step) -> 3/4 of epilogue hidden under
// compute. s=6,7 refill slots prime the next strip's ring. All R6 invariants:
// full-line psi reads, XOR-swizzled B LDS (128 KB), ping-pong distance-2
// epilogue WITH sched_barrier(0) per pass, 1 KB NT stores, one __syncthreads.
// LDS 144 KB caps occupancy at 2 waves/SIMD -> allocator has no incentive to
// spill the ~170 live VGPRs (R5/R7 precedent under identical LDS pressure).
__global__ __launch_bounds__(512, 1) void kgemm(
    const float* __restrict__ psi, const unsigned short* __restrict__ Ut,
    float* __restrict__ out) {
    __shared__ unsigned short Bls[NN];          // 128 KB, swizzled 16B slots
    __shared__ float Escr[8][512];              // 16 KB: 2 KB/wave (2 x 1 KB halves)
    const int t = threadIdx.x;

    // stage Ut -> LDS: slot(r,j) = r*32 + (j ^ (r&7)), 16B units
    const s8bf* Ug = (const s8bf*)Ut;
    s8bf* Bg = (s8bf*)Bls;
#pragma unroll
    for (int i = 0; i < 16; ++i) {
        int g = i * 512 + t;                    // 16B-chunk id in [0, 8192)
        int r = g >> 5, j = g & 31;
        Bg[(r << 5) | (j ^ (r & 7))] = Ug[g];
    }
    __syncthreads();

    const int w = t >> 6, lane = t & 63;
    const int c = lane & 15, q = lane >> 4;
    const f32x4* psi4 = (const f32x4*)psi;
    f32x4* out4 = (f32x4*)out;
    float* Ebase = &Escr[w][0];

    const int bb0 = blockIdx.x * 512 + w * 16;  // strip k rows: bb0 + k*128
    const size_t rl0 = (size_t)(bb0 +       c) * 64;
    const size_t rl1 = (size_t)(bb0 + 128 + c) * 64;
    const size_t rl2 = (size_t)(bb0 + 256 + c) * 64;
    const size_t rl3 = (size_t)(bb0 + 384 + c) * 64;

    f32x4 accA[16], accB[16], pb[2][2];

    // prime ring for strip 0 (after barrier — R13 showed hoisting regresses)
    pb[0][0] = psi4[rl0 + q*2];     pb[0][1] = psi4[rl0 + q*2 + 1];
    pb[1][0] = psi4[rl0 + 8 + q*2]; pb[1][1] = psi4[rl0 + 8 + q*2 + 1];

    // STRIP 0 -> accA (no epilogue yet)
#pragma unroll
    for (int i = 0; i < 16; ++i) accA[i] = (f32x4)0.f;
#pragma unroll
    for (int s = 0; s < 8; ++s) main_step(s, psi4, Bg, c, q, rl0, rl1, pb, accA);

    // STRIP 1 -> accB, interleave EPI(strip 0, accA)
#pragma unroll
    for (int i = 0; i < 16; ++i) accB[i] = (f32x4)0.f;
#pragma unroll
    for (int s = 0; s < 8; ++s) {
        main_step(s, psi4, Bg, c, q, rl1, rl2, pb, accB);
        epi_pass(2*s,     c, q, lane, Ebase, accA, out4, bb0);
        epi_pass(2*s + 1, c, q, lane, Ebase, accA, out4, bb0);
    }

    // STRIP 2 -> accA, interleave EPI(strip 1, accB)
#pragma unroll
    for (int i = 0; i < 16; ++i) accA[i] = (f32x4)0.f;
#pragma unroll
    for (int s = 0; s < 8; ++s) {
        main_step(s, psi4, Bg, c, q, rl2, rl3, pb, accA);
        epi_pass(2*s,     c, q, lane, Ebase, accB, out4, bb0 + 128);
        epi_pass(2*s + 1, c, q, lane, Ebase, accB, out4, bb0 + 128);
    }

    // STRIP 3 -> accB, interleave EPI(strip 2, accA); rlN = self (harmless dups)
#pragma unroll
    for (int i = 0; i < 16; ++i) accB[i] = (f32x4)0.f;
#pragma unroll
    for (int s = 0; s < 8; ++s) {
        main_step(s, psi4, Bg, c, q, rl3, rl3, pb, accB);
        epi_pass(2*s,     c, q, lane, Ebase, accA, out4, bb0 + 256);
        epi_pass(2*s + 1, c, q, lane, Ebase, accA, out4, bb0 + 256);
    }

    // drain: EPI(strip 3, accB)
#pragma unroll
    for (int p = 0; p < 16; ++p)
        epi_pass(p, c, q, lane, Ebase, accB, out4, bb0 + 384);
}

extern "C" void kernel_launch(void* const* d_in, const int* in_sizes, int n_in,
                              void* d_out, int out_size, void* d_ws, size_t ws_size,
                              hipStream_t stream) {
    const float* psi = (const float*)d_in[0];   // [8,4096,4,256] f32
    const float* H   = (const float*)d_in[1];   // [4,256,256]    f32
    float* out = (float*)d_out;                 // [8,4096,4,256] f32

    float2* M2c = (float2*)d_ws;                // NN complex
    float2* M3c = M2c + NN;                     // NN complex
    unsigned short* Ut = (unsigned short*)(M3c + NN);  // NN bf16 (Ut[col][k])

    dim3 cb(16, 16, 4), cg(16, 16);
    kmm<<<cg, cb, 0, stream>>>(H, M2c, M3c, Ut, 0);   // M2 = M*M
    kmm<<<cg, cb, 0, stream>>>(H, M2c, M3c, Ut, 1);   // M3 = M2*M
    kmm<<<cg, cb, 0, stream>>>(H, M2c, M3c, Ut, 2);   // Ut = bf16(Re(U))^T
    kgemm<<<256, 512, 0, stream>>>(psi, Ut, out);
}

// Round 17
// 72.298 us; speedup vs baseline: 1.0594x; 1.0594x over previous
//
#include <hip/hip_runtime.h>
#include <hip/hip_bf16.h>

#define NDIM 256
#define NN (NDIM*NDIM)

typedef __attribute__((ext_vector_type(8))) short s8bf;    // 8 x bf16 (4 VGPRs)
typedef __attribute__((ext_vector_type(4))) float f32x4;   // MFMA accum / native float4

__device__ __forceinline__ unsigned short f2bf(float f) {
    union { float f; unsigned u; } v; v.f = f;
    unsigned u = v.u;
    return (unsigned short)((u + 0x7FFFu + ((u >> 16) & 1u)) >> 16);  // RNE
}
__device__ __forceinline__ short f2bfs(float f) {          // compiler emits v_cvt_pk_bf16_f32
    __hip_bfloat16 h = __float2bfloat16(f);
    union { __hip_bfloat16 h; short s; } v; v.h = h;
    return v.s;
}

// ---------------- expm pipeline: U = B0 + M3*(B1 + M3/720) ----------------
// M = H1 - i*H0. deg-6 Taylor; truncation ~1e-4 << bf16 noise.
// 1024 thr (16,16,4): K split 4 ways across tz + 2-way sub-accumulators.
__global__ __launch_bounds__(1024) void kmm(
    const float* __restrict__ H, float2* __restrict__ M2c, float2* __restrict__ M3c,
    unsigned short* __restrict__ Ut, int mode) {
    __shared__ float2 As[16][257];
    __shared__ float2 Bs[256][17];
    __shared__ float2 Rs[3][16][17];
    const int tx = threadIdx.x, ty = threadIdx.y, tz = threadIdx.z;
    const int tid = (tz * 16 + ty) * 16 + tx;
    const int r0 = blockIdx.y * 16, c0 = blockIdx.x * 16;

#pragma unroll
    for (int i = 0; i < 4; ++i) {               // A panel: 16 rows x 256 k
        int idx = i * 1024 + tid;
        int r = idx >> 8, k = idx & 255;
        float2 a;
        if (mode == 0)      { a.x = H[NN + (r0+r)*NDIM + k]; a.y = -H[(r0+r)*NDIM + k]; }
        else if (mode == 1) a = M2c[(r0+r)*NDIM + k];
        else                a = M3c[(r0+r)*NDIM + k];
        As[r][k] = a;
    }
#pragma unroll
    for (int i = 0; i < 4; ++i) {               // B panel: 256 k x 16 cols
        int idx = i * 1024 + tid;
        int k = idx >> 4, cc = idx & 15;
        float2 b;
        if (mode <= 1) { b.x = H[NN + k*NDIM + c0+cc]; b.y = -H[k*NDIM + c0+cc]; }
        else {
            int g = k * NDIM + c0 + cc;
            float mr = H[NN + g], mi = -H[g];
            float2 m2 = M2c[g], m3 = M3c[g];
            float di = (k == c0 + cc) ? 1.f : 0.f;
            b.x = di*(1.f/6.f) + mr*(1.f/24.f) + m2.x*(1.f/120.f) + m3.x*(1.f/720.f);
            b.y =                mi*(1.f/24.f) + m2.y*(1.f/120.f) + m3.y*(1.f/720.f);
        }
        Bs[k][cc] = b;
    }
    __syncthreads();

    float sr0=0.f, si0=0.f, sr1=0.f, si1=0.f;
#pragma unroll 8
    for (int k = tz*64; k < tz*64 + 64; k += 2) {
        float2 a = As[ty][k], b = Bs[k][tx];
        sr0 = fmaf(a.x, b.x, sr0); sr0 = fmaf(-a.y, b.y, sr0);
        si0 = fmaf(a.x, b.y, si0); si0 = fmaf(a.y, b.x, si0);
        float2 a1 = As[ty][k+1], b1 = Bs[k+1][tx];
        sr1 = fmaf(a1.x, b1.x, sr1); sr1 = fmaf(-a1.y, b1.y, sr1);
        si1 = fmaf(a1.x, b1.y, si1); si1 = fmaf(a1.y, b1.x, si1);
    }
    float sr = sr0 + sr1, si = si0 + si1;
    if (tz > 0) Rs[tz-1][ty][tx] = make_float2(sr, si);
    __syncthreads();
    if (tz == 0) {
        sr += Rs[0][ty][tx].x + Rs[1][ty][tx].x + Rs[2][ty][tx].x;
        si += Rs[0][ty][tx].y + Rs[1][ty][tx].y + Rs[2][ty][tx].y;
        int d = r0 + ty, e = c0 + tx;
        if (mode == 0)      M2c[d*NDIM + e] = make_float2(sr, si);
        else if (mode == 1) M3c[d*NDIM + e] = make_float2(sr, si);
        else {
            int g = d * NDIM + e;
            float ur = sr + ((d == e) ? 1.f : 0.f) + H[NN + g] + M2c[g].x * 0.5f;
            Ut[e * NDIM + d] = f2bf(ur);         // transposed: Ut[col][k]
        }
    }
}

// ---------------- main GEMM: out[131072 x 256] = psi @ Re(U) ----------------
// BYTE-EXACT round-6/round-14 kernel (71.5/72.2 us total — best of 16 rounds;
// every structural deviation tied or regressed: deeper prefetch R7, zero-LDS
// R8/9, 32x32 hybrid R10, DMA+counted-vmcnt R11, minimal-32 R12, prefetch
// hoist R13, strip-pipeline R15/16). 1024 thr = 16 waves x 16 rows (acc[16] =
// 64 VGPR). B (Ut, 128 KB bf16) staged once per block, XOR-swizzled. psi
// streamed with depth-2 prefetch, full-line reads. Epilogue: 1-row passes
// ping-ponged between two 1 KB halves (distance-2 reuse, sched_barrier(0)
// pinned) -> full-line 1 KB NT stores. LDS = 160 KiB exact.
__global__ __launch_bounds__(1024, 4) void kgemm(
    const float* __restrict__ psi, const unsigned short* __restrict__ Ut,
    float* __restrict__ out) {
    __shared__ unsigned short Bls[NN];          // 128 KB, swizzled 16B slots
    __shared__ float Escr[16][512];             // 32 KB: 2 KB/wave (2 x 1 KB halves)
    const int t = threadIdx.x;

    // stage Ut -> LDS: slot(r,j) = r*32 + (j ^ (r&7)), 16B units
    const s8bf* Ug = (const s8bf*)Ut;
    s8bf* Bg = (s8bf*)Bls;
#pragma unroll
    for (int i = 0; i < 8; ++i) {
        int g = i * 1024 + t;                   // 16B-chunk id in [0, 8192)
        int r = g >> 5, j = g & 31;
        Bg[(r << 5) | (j ^ (r & 7))] = Ug[g];
    }
    __syncthreads();

    const int w = t >> 6, lane = t & 63;
    const int c = lane & 15, q = lane >> 4;
    const f32x4* psi4 = (const f32x4*)psi;
    f32x4* out4 = (f32x4*)out;
    float* Ebase = &Escr[w][0];

#pragma unroll 1
    for (int st = 0; st < 2; ++st) {
        const int base = blockIdx.x * 512 + st * 256 + w * 16;
        const size_t rl = (size_t)(base + c) * 64;     // f32x4 units

        f32x4 acc[16];
#pragma unroll
        for (int i = 0; i < 16; ++i) acc[i] = (f32x4)0.f;

        f32x4 pb[2][2];                          // depth-2 prefetch ring
        pb[0][0] = psi4[rl + q*2];     pb[0][1] = psi4[rl + q*2 + 1];
        pb[1][0] = psi4[rl + 8 + q*2]; pb[1][1] = psi4[rl + 8 + q*2 + 1];

#pragma unroll
        for (int s = 0; s < 8; ++s) {
            s8bf a;
#pragma unroll
            for (int j = 0; j < 4; ++j) {
                a[j]     = f2bfs(pb[s & 1][0][j]);
                a[j + 4] = f2bfs(pb[s & 1][1][j]);
            }
            if (s < 6) {                         // refill slot for step s+2
                int o = (s + 2) * 8 + q * 2;
                pb[s & 1][0] = psi4[rl + o];
                pb[s & 1][1] = psi4[rl + o + 1];
            }
#pragma unroll
            for (int ct = 0; ct < 16; ++ct) {
                int rr = ct * 16 + c;
                s8bf bb = Bg[(rr << 5) | ((s*4 + q) ^ (rr & 7))];
                acc[ct] = __builtin_amdgcn_mfma_f32_16x16x32_bf16(a, bb, acc[ct], 0, 0, 0);
            }
        }

        // epilogue: 16 passes x 1 row, ping-pong 1 KB halves, full-line stores
#pragma unroll
        for (int p = 0; p < 16; ++p) {
            const int qq = p >> 2, rr = p & 3;
            float* E = Ebase + (p & 1) * 256;
            if (q == qq) {
#pragma unroll
                for (int ct = 0; ct < 16; ++ct)
                    E[ct * 16 + c] = acc[ct][rr];
            }
            f32x4 vv = *(const f32x4*)(&E[lane * 4]);
            __builtin_nontemporal_store(vv, &out4[(size_t)(base + p) * 64 + lane]);
            __builtin_amdgcn_sched_barrier(0);   // pin pass ordering (WAR safety)
        }
    }
}

extern "C" void kernel_launch(void* const* d_in, const int* in_sizes, int n_in,
                              void* d_out, int out_size, void* d_ws, size_t ws_size,
                              hipStream_t stream) {
    const float* psi = (const float*)d_in[0];   // [8,4096,4,256] f32
    const float* H   = (const float*)d_in[1];   // [4,256,256]    f32
    float* out = (float*)d_out;                 // [8,4096,4,256] f32

    float2* M2c = (float2*)d_ws;                // NN complex
    float2* M3c = M2c + NN;                     // NN complex
    unsigned short* Ut = (unsigned short*)(M3c + NN);  // NN bf16 (Ut[col][k])

    dim3 cb(16, 16, 4), cg(16, 16);
    kmm<<<cg, cb, 0, stream>>>(H, M2c, M3c, Ut, 0);   // M2 = M*M
    kmm<<<cg, cb, 0, stream>>>(H, M2c, M3c, Ut, 1);   // M3 = M2*M
    kmm<<<cg, cb, 0, stream>>>(H, M2c, M3c, Ut, 2);   // Ut = bf16(Re(U))^T
    kgemm<<<256, 1024, 0, stream>>>(psi, Ut, out);
}